// Round 3
// baseline (127.721 us; speedup 1.0000x reference)
//
#include <hip/hip_runtime.h>
#include <hip/hip_bf16.h>
#include <cstdint>
#include <cstddef>

#define N_NODES 8192
#define F_IN 512
#define F_OUT 64
#define LOG2E 1.44269504f

typedef __attribute__((ext_vector_type(8))) short short8v;  // 8 bf16 = 4 VGPRs
typedef __attribute__((ext_vector_type(4))) float f32x4;
typedef __attribute__((ext_vector_type(4))) int i32x4;
typedef __attribute__((ext_vector_type(4))) unsigned int u32x4;

static __device__ __forceinline__ unsigned short f2bf(float f) {
    union { float f; unsigned u; } v; v.f = f;
    unsigned u = v.u + 0x7FFFu + ((v.u >> 16) & 1u);   // RNE
    return (unsigned short)(u >> 16);
}
static __device__ __forceinline__ float bf2f(unsigned short b) {
    union { unsigned u; float f; } v; v.u = ((unsigned)b) << 16;
    return v.f;
}
// packed f32x2 -> bf16x2 (RNE), one VALU instr
static __device__ __forceinline__ unsigned cvt_pk_bf16(float lo, float hi) {
    unsigned r;
    asm("v_cvt_pk_bf16_f32 %0, %1, %2" : "=v"(r) : "v"(lo), "v"(hi));
    return r;
}

// ---------------------------------------------------------------------------
// Kernel 0: convert W (512x64 f32) into fragment-ordered bf16 hi/lo buffers.
// ---------------------------------------------------------------------------
__global__ __launch_bounds__(256)
void gat_wconv(const float* __restrict__ W, unsigned short* __restrict__ whf,
               unsigned short* __restrict__ wlf) {
    const int t = blockIdx.x * 256 + threadIdx.x;   // 0..4095
    const int tile = t >> 6, lane = t & 63;
    const int kt = tile >> 2, ct = tile & 3;
    const int k0 = kt * 32 + ((lane >> 4) << 3);
    const int c  = ct * 16 + (lane & 15);
    short8v h, l;
    #pragma unroll
    for (int i = 0; i < 8; ++i) {
        float v = W[(size_t)(k0 + i) * F_OUT + c];
        unsigned short hb = f2bf(v);
        h[i] = (short)hb;
        l[i] = (short)f2bf(v - bf2f(hb));
    }
    const size_t dst = (size_t)tile * 512 + (size_t)lane * 8;
    *(short8v*)(whf + dst) = h;
    *(short8v*)(wlf + dst) = l;
}

// ---------------------------------------------------------------------------
// Kernel 1: Wh = x@W via bf16 hi/lo split MFMA, s1/s2 (pre-scaled by log2e),
// fragment-ordered bf16 whtf. 256 blocks x 128 threads.
// ---------------------------------------------------------------------------
__global__ __launch_bounds__(128)
void gat_prep(const float* __restrict__ x, const unsigned short* __restrict__ whf,
              const unsigned short* __restrict__ wlf, const float* __restrict__ a,
              unsigned short* __restrict__ whtf,
              float* __restrict__ s1, float* __restrict__ s2) {
    __shared__ unsigned short ldsT[64][40];   // [col][row], 80B rows
    const int tid = threadIdx.x;
    const int lane = tid & 63;
    const int wv = tid >> 6;                  // 0..1
    const int l15 = lane & 15, g = lane >> 4;
    const int jt = blockIdx.x;                // jtile 0..255
    const int row0 = jt * 32 + wv * 16;

    f32x4 acc[4] = {{0.f,0.f,0.f,0.f},{0.f,0.f,0.f,0.f},{0.f,0.f,0.f,0.f},{0.f,0.f,0.f,0.f}};

    const float* xp = x + (size_t)(row0 + l15) * F_IN + g * 8;
    for (int kt = 0; kt < 16; ++kt) {
        float4 v0 = *(const float4*)(xp);
        float4 v1 = *(const float4*)(xp + 4);
        xp += 32;
        float vv[8] = {v0.x, v0.y, v0.z, v0.w, v1.x, v1.y, v1.z, v1.w};
        short8v xh, xl;
        #pragma unroll
        for (int i = 0; i < 8; ++i) {
            unsigned short hb = f2bf(vv[i]);
            xh[i] = (short)hb;
            xl[i] = (short)f2bf(vv[i] - bf2f(hb));
        }
        const unsigned short* wp = whf + (size_t)(kt * 4) * 512 + (size_t)lane * 8;
        const unsigned short* lp = wlf + (size_t)(kt * 4) * 512 + (size_t)lane * 8;
        #pragma unroll
        for (int ct = 0; ct < 4; ++ct) {
            short8v wh = *(const short8v*)(wp + ct * 512);
            short8v wl = *(const short8v*)(lp + ct * 512);
            acc[ct] = __builtin_amdgcn_mfma_f32_16x16x32_bf16(xh, wh, acc[ct], 0, 0, 0);
            acc[ct] = __builtin_amdgcn_mfma_f32_16x16x32_bf16(xl, wh, acc[ct], 0, 0, 0);
            acc[ct] = __builtin_amdgcn_mfma_f32_16x16x32_bf16(xh, wl, acc[ct], 0, 0, 0);
        }
    }

    // s1/s2: C-frag is col = ct*16+l15, local row = 4g+r  (scaled by log2e)
    #pragma unroll
    for (int r = 0; r < 4; ++r) {
        float p1 = 0.f, p2 = 0.f;
        #pragma unroll
        for (int ct = 0; ct < 4; ++ct) {
            p1 = fmaf(acc[ct][r], a[ct * 16 + l15], p1);
            p2 = fmaf(acc[ct][r], a[64 + ct * 16 + l15], p2);
        }
        p1 += __shfl_xor(p1, 1); p2 += __shfl_xor(p2, 1);
        p1 += __shfl_xor(p1, 2); p2 += __shfl_xor(p2, 2);
        p1 += __shfl_xor(p1, 4); p2 += __shfl_xor(p2, 4);
        p1 += __shfl_xor(p1, 8); p2 += __shfl_xor(p2, 8);
        if (l15 == 0) {
            s1[row0 + g * 4 + r] = p1 * LOG2E;
            s2[row0 + g * 4 + r] = p2 * LOG2E;
        }
    }

    // transpose to [col][row] bf16 in LDS
    #pragma unroll
    for (int ct = 0; ct < 4; ++ct) {
        ushort4 pk;
        pk.x = f2bf(acc[ct][0]); pk.y = f2bf(acc[ct][1]);
        pk.z = f2bf(acc[ct][2]); pk.w = f2bf(acc[ct][3]);
        *(ushort4*)&ldsT[ct * 16 + l15][wv * 16 + g * 4] = pk;
    }
    __syncthreads();

    // emit fragment-ordered whtf
    #pragma unroll
    for (int fl = 0; fl < 2; ++fl) {
        const int ft = wv * 2 + fl;
        short8v sv = *(const short8v*)&ldsT[ft * 16 + l15][g * 8];
        *(short8v*)(whtf + ((size_t)jt * 4 + ft) * 512 + (size_t)lane * 8) = sv;
    }
}

// ---------------------------------------------------------------------------
// Kernel 2: fused masked-softmax attention + PV via bf16 MFMA.
// nt-hinted adj stream (read-once, don't evict whtf from L2), register
// prefetch of next iteration's adj/s2, exp2-domain scores, packed bf16 cvt.
// ---------------------------------------------------------------------------
__global__ __launch_bounds__(512)
void gat_main(const int* __restrict__ adj, const unsigned short* __restrict__ whtf,
              const float* __restrict__ s1, const float* __restrict__ s2,
              float* __restrict__ out) {
    __shared__ float nums[8][16][64];   // 32 KB partial numerators
    __shared__ float dens[8][16];       // partial denominators
    const int tid  = threadIdx.x;
    const int lane = tid & 63;
    const int wv   = tid >> 6;          // 0..7: j-split
    const int l15  = lane & 15, g = lane >> 4;
    const int r0   = blockIdx.x * 16;
    const int row  = r0 + l15;
    const float s1r = s1[row];          // already in exp2 domain
    const int j0 = wv * 1024;

    const i32x4*  ap  = (const i32x4*)(adj + (size_t)row * N_NODES + j0 + g * 8);
    const float4* s2p = (const float4*)(s2 + j0 + g * 8);
    const unsigned short* bp = whtf + ((size_t)(j0 >> 5) * 4) * 512 + (size_t)lane * 8;

    f32x4 acc0 = {0.f, 0.f, 0.f, 0.f};
    f32x4 acc1 = acc0, acc2 = acc0, acc3 = acc0;
    float dsum = 0.f;

    // prologue: first iteration's adj + s2 in flight
    i32x4  aj0 = __builtin_nontemporal_load(ap);
    i32x4  aj1 = __builtin_nontemporal_load(ap + 1);
    float4 sa  = s2p[0];
    float4 sb  = s2p[1];

    for (int t = 0; t < 32; ++t) {
        const i32x4  caj0 = aj0, caj1 = aj1;
        const float4 csa = sa, csb = sb;
        if (t < 31) {                  // prefetch next iteration (uniform branch)
            ap  += 8; s2p += 8;
            aj0 = __builtin_nontemporal_load(ap);
            aj1 = __builtin_nontemporal_load(ap + 1);
            sa  = s2p[0];
            sb  = s2p[1];
        }

        short8v b0 = *(const short8v*)(bp);
        short8v b1 = *(const short8v*)(bp + 512);
        short8v b2 = *(const short8v*)(bp + 1024);
        short8v b3 = *(const short8v*)(bp + 1536);
        bp += 2048;

        float w0, w1, w2, w3, w4, w5, w6, w7;
        #define GAT_EL(wvar, ajv, s2v) do { \
            float e = s1r + (s2v); e = fmaxf(e, 0.2f * e); \
            float ex = __builtin_amdgcn_exp2f(e); \
            wvar = ((ajv) > 0) ? ex : 0.f; dsum += wvar; } while (0);
        GAT_EL(w0, caj0[0], csa.x) GAT_EL(w1, caj0[1], csa.y)
        GAT_EL(w2, caj0[2], csa.z) GAT_EL(w3, caj0[3], csa.w)
        GAT_EL(w4, caj1[0], csb.x) GAT_EL(w5, caj1[1], csb.y)
        GAT_EL(w6, caj1[2], csb.z) GAT_EL(w7, caj1[3], csb.w)
        #undef GAT_EL

        u32x4 au;
        au[0] = cvt_pk_bf16(w0, w1);
        au[1] = cvt_pk_bf16(w2, w3);
        au[2] = cvt_pk_bf16(w4, w5);
        au[3] = cvt_pk_bf16(w6, w7);
        short8v afrag = __builtin_bit_cast(short8v, au);

        acc0 = __builtin_amdgcn_mfma_f32_16x16x32_bf16(afrag, b0, acc0, 0, 0, 0);
        acc1 = __builtin_amdgcn_mfma_f32_16x16x32_bf16(afrag, b1, acc1, 0, 0, 0);
        acc2 = __builtin_amdgcn_mfma_f32_16x16x32_bf16(afrag, b2, acc2, 0, 0, 0);
        acc3 = __builtin_amdgcn_mfma_f32_16x16x32_bf16(afrag, b3, acc3, 0, 0, 0);
    }

    // row-sum of dsum across the 4 k-groups (lanes with same l15)
    dsum += __shfl_xor(dsum, 16);
    dsum += __shfl_xor(dsum, 32);

    // C-frag layout: col = lane&15, row = 4*(lane>>4) + reg
    #pragma unroll
    for (int r = 0; r < 4; ++r) {
        nums[wv][g * 4 + r][0 * 16 + l15] = acc0[r];
        nums[wv][g * 4 + r][1 * 16 + l15] = acc1[r];
        nums[wv][g * 4 + r][2 * 16 + l15] = acc2[r];
        nums[wv][g * 4 + r][3 * 16 + l15] = acc3[r];
    }
    if (lane < 16) dens[wv][lane] = dsum;
    __syncthreads();

    // combine the 8 j-partials, normalize, ELU, write
    for (int o = tid; o < 16 * 64; o += 512) {
        const int r = o >> 6, f = o & 63;
        float num = 0.f, den = 0.f;
        #pragma unroll
        for (int q = 0; q < 8; ++q) { num += nums[q][r][f]; den += dens[q][r]; }
        float h = num / den;
        out[(size_t)(r0 + r) * 64 + f] = h > 0.f ? h : __expf(h) - 1.f;
    }
}

extern "C" void kernel_launch(void* const* d_in, const int* in_sizes, int n_in,
                              void* d_out, int out_size, void* d_ws, size_t ws_size,
                              hipStream_t stream) {
    const float* x      = (const float*)d_in[0];
    const int*   adj    = (const int*)d_in[1];
    const float* weight = (const float*)d_in[2];
    const float* a      = (const float*)d_in[3];
    float* out = (float*)d_out;

    // ws layout: whtf (1 MB) | s1 (32 KB) | s2 (32 KB) | whf (64 KB) | wlf (64 KB)
    char* ws = (char*)d_ws;
    unsigned short* whtf = (unsigned short*)ws;
    float* s1            = (float*)(ws + 1048576);
    float* s2            = (float*)(ws + 1048576 + 32768);
    unsigned short* whf  = (unsigned short*)(ws + 1048576 + 65536);
    unsigned short* wlf  = (unsigned short*)(ws + 1048576 + 65536 + 65536);

    gat_wconv<<<16, 256, 0, stream>>>(weight, whf, wlf);
    gat_prep<<<N_NODES / 32, 128, 0, stream>>>(x, whf, wlf, a, whtf, s1, s2);
    gat_main<<<N_NODES / 16, 512, 0, stream>>>(adj, whtf, s1, s2, out);
}

// Round 4
// 89.318 us; speedup vs baseline: 1.4300x; 1.4300x over previous
//
#include <hip/hip_runtime.h>
#include <hip/hip_bf16.h>
#include <cstdint>
#include <cstddef>

#define N_NODES 8192
#define F_IN 512
#define F_OUT 64
#define LOG2E 1.44269504f

#define JSPLIT 4
#define JPB (N_NODES / JSPLIT)   // 2048 j per block
#define JC 256                   // j per staged chunk (32 KB LDS)
#define NCHUNK (JPB / JC)        // 8

typedef __attribute__((ext_vector_type(8))) short short8v;  // 8 bf16 = 4 VGPRs
typedef __attribute__((ext_vector_type(4))) float f32x4;
typedef __attribute__((ext_vector_type(4))) int i32x4;
typedef __attribute__((ext_vector_type(4))) unsigned int u32x4;

static __device__ __forceinline__ unsigned short f2bf(float f) {
    union { float f; unsigned u; } v; v.f = f;
    unsigned u = v.u + 0x7FFFu + ((v.u >> 16) & 1u);   // RNE
    return (unsigned short)(u >> 16);
}
static __device__ __forceinline__ float bf2f(unsigned short b) {
    union { unsigned u; float f; } v; v.u = ((unsigned)b) << 16;
    return v.f;
}
static __device__ __forceinline__ unsigned cvt_pk_bf16(float lo, float hi) {
    unsigned r;
    asm("v_cvt_pk_bf16_f32 %0, %1, %2" : "=v"(r) : "v"(lo), "v"(hi));
    return r;
}

// ---------------------------------------------------------------------------
// Kernel 0: W (512x64 f32) -> fragment-ordered bf16 hi/lo buffers.
// ---------------------------------------------------------------------------
__global__ __launch_bounds__(256)
void gat_wconv(const float* __restrict__ W, unsigned short* __restrict__ whf,
               unsigned short* __restrict__ wlf) {
    const int t = blockIdx.x * 256 + threadIdx.x;   // 0..4095
    const int tile = t >> 6, lane = t & 63;
    const int kt = tile >> 2, ct = tile & 3;
    const int k0 = kt * 32 + ((lane >> 4) << 3);
    const int c  = ct * 16 + (lane & 15);
    short8v h, l;
    #pragma unroll
    for (int i = 0; i < 8; ++i) {
        float v = W[(size_t)(k0 + i) * F_OUT + c];
        unsigned short hb = f2bf(v);
        h[i] = (short)hb;
        l[i] = (short)f2bf(v - bf2f(hb));
    }
    const size_t dst = (size_t)tile * 512 + (size_t)lane * 8;
    *(short8v*)(whf + dst) = h;
    *(short8v*)(wlf + dst) = l;
}

// ---------------------------------------------------------------------------
// Kernel 1: Wh = x@W via bf16 hi/lo split MFMA, s1/s2 (exp2-domain),
// fragment-ordered bf16 whtf. 256 blocks x 128 threads. x loads 4-kt batched.
// ---------------------------------------------------------------------------
__global__ __launch_bounds__(128)
void gat_prep(const float* __restrict__ x, const unsigned short* __restrict__ whf,
              const unsigned short* __restrict__ wlf, const float* __restrict__ a,
              unsigned short* __restrict__ whtf,
              float* __restrict__ s1, float* __restrict__ s2) {
    __shared__ unsigned short ldsT[64][40];   // [col][row], 80B rows
    const int tid = threadIdx.x;
    const int lane = tid & 63;
    const int wv = tid >> 6;                  // 0..1
    const int l15 = lane & 15, g = lane >> 4;
    const int jt = blockIdx.x;                // jtile 0..255
    const int row0 = jt * 32 + wv * 16;

    f32x4 acc[4] = {{0.f,0.f,0.f,0.f},{0.f,0.f,0.f,0.f},{0.f,0.f,0.f,0.f},{0.f,0.f,0.f,0.f}};

    const float4* xp = (const float4*)(x + (size_t)(row0 + l15) * F_IN) + g * 2;
    for (int kb = 0; kb < 4; ++kb) {
        float4 v[8];
        #pragma unroll
        for (int q = 0; q < 4; ++q) {         // batch 4 kt's loads -> 1 round trip
            v[2 * q]     = xp[q * 8];
            v[2 * q + 1] = xp[q * 8 + 1];
        }
        xp += 32;
        #pragma unroll
        for (int q = 0; q < 4; ++q) {
            const int kt = kb * 4 + q;
            float vv[8] = {v[2*q].x, v[2*q].y, v[2*q].z, v[2*q].w,
                           v[2*q+1].x, v[2*q+1].y, v[2*q+1].z, v[2*q+1].w};
            short8v xh, xl;
            #pragma unroll
            for (int i = 0; i < 8; ++i) {
                unsigned short hb = f2bf(vv[i]);
                xh[i] = (short)hb;
                xl[i] = (short)f2bf(vv[i] - bf2f(hb));
            }
            const unsigned short* wp = whf + (size_t)(kt * 4) * 512 + (size_t)lane * 8;
            const unsigned short* lp = wlf + (size_t)(kt * 4) * 512 + (size_t)lane * 8;
            #pragma unroll
            for (int ct = 0; ct < 4; ++ct) {
                short8v wh = *(const short8v*)(wp + ct * 512);
                short8v wl = *(const short8v*)(lp + ct * 512);
                acc[ct] = __builtin_amdgcn_mfma_f32_16x16x32_bf16(xh, wh, acc[ct], 0, 0, 0);
                acc[ct] = __builtin_amdgcn_mfma_f32_16x16x32_bf16(xl, wh, acc[ct], 0, 0, 0);
                acc[ct] = __builtin_amdgcn_mfma_f32_16x16x32_bf16(xh, wl, acc[ct], 0, 0, 0);
            }
        }
    }

    // s1/s2 (scaled by log2e): C-frag col = ct*16+l15, local row = 4g+r
    #pragma unroll
    for (int r = 0; r < 4; ++r) {
        float p1 = 0.f, p2 = 0.f;
        #pragma unroll
        for (int ct = 0; ct < 4; ++ct) {
            p1 = fmaf(acc[ct][r], a[ct * 16 + l15], p1);
            p2 = fmaf(acc[ct][r], a[64 + ct * 16 + l15], p2);
        }
        p1 += __shfl_xor(p1, 1); p2 += __shfl_xor(p2, 1);
        p1 += __shfl_xor(p1, 2); p2 += __shfl_xor(p2, 2);
        p1 += __shfl_xor(p1, 4); p2 += __shfl_xor(p2, 4);
        p1 += __shfl_xor(p1, 8); p2 += __shfl_xor(p2, 8);
        if (l15 == 0) {
            s1[row0 + g * 4 + r] = p1 * LOG2E;
            s2[row0 + g * 4 + r] = p2 * LOG2E;
        }
    }

    // transpose to [col][row] bf16 in LDS
    #pragma unroll
    for (int ct = 0; ct < 4; ++ct) {
        ushort4 pk;
        pk.x = f2bf(acc[ct][0]); pk.y = f2bf(acc[ct][1]);
        pk.z = f2bf(acc[ct][2]); pk.w = f2bf(acc[ct][3]);
        *(ushort4*)&ldsT[ct * 16 + l15][wv * 16 + g * 4] = pk;
    }
    __syncthreads();

    // emit fragment-ordered whtf
    #pragma unroll
    for (int fl = 0; fl < 2; ++fl) {
        const int ft = wv * 2 + fl;
        short8v sv = *(const short8v*)&ldsT[ft * 16 + l15][g * 8];
        *(short8v*)(whtf + ((size_t)jt * 4 + ft) * 512 + (size_t)lane * 8) = sv;
    }
}

// ---------------------------------------------------------------------------
// Kernel 2: fused masked-softmax attention + PV via bf16 MFMA.
// Block = 128 rows x 2048 j (grid 64x4 = 256). All 8 waves share a 32 KB
// whtf chunk staged in LDS (double-buffered, global_load_lds width=16).
// Writes j-split partial numerators/denominators; combine kernel finishes.
// ---------------------------------------------------------------------------
__global__ __launch_bounds__(512)
void gat_main(const int* __restrict__ adj, const unsigned short* __restrict__ whtf,
              const float* __restrict__ s1, const float* __restrict__ s2,
              float* __restrict__ numpart, float* __restrict__ denpart) {
    __shared__ unsigned short lds[2][JC * F_OUT];   // 2 x 32 KB
    const int tid  = threadIdx.x;
    const int lane = tid & 63;
    const int wv   = tid >> 6;                // 0..7: row-tile within block
    const int l15  = lane & 15, g = lane >> 4;
    const int rg   = blockIdx.x >> 2;         // 0..63 row-group (128 rows)
    const int js   = blockIdx.x & 3;          // j-split
    const int rowbase = rg * 128 + wv * 16;
    const int row  = rowbase + l15;
    const int j0   = js * JPB;
    const float s1r = s1[row];                // exp2 domain

    const char* gbase = (const char*)whtf + (size_t)j0 * 128;   // 128 B per j column
    const int*   aprow = adj + (size_t)row * N_NODES + j0 + g * 8;
    const float* s2b   = s2 + j0 + g * 8;

    f32x4 acc0 = {0.f, 0.f, 0.f, 0.f};
    f32x4 acc1 = acc0, acc2 = acc0, acc3 = acc0;
    float dsum = 0.f;

    #define STAGE(ch, buf) do { \
        const char* _g = gbase + (size_t)(ch) * 32768 + (size_t)tid * 16; \
        char* _l = (char*)&lds[buf][0] + (size_t)wv * 1024; \
        _Pragma("unroll") \
        for (int _i = 0; _i < 4; ++_i) \
            __builtin_amdgcn_global_load_lds( \
                (const __attribute__((address_space(1))) void*)(_g + _i * 8192), \
                (__attribute__((address_space(3))) void*)(_l + _i * 8192), 16, 0, 0); \
    } while (0)

    STAGE(0, 0);
    __syncthreads();    // drains vmcnt+lgkmcnt before barrier (compiler semantics)

    for (int ch = 0; ch < NCHUNK; ++ch) {
        const int cur = ch & 1;
        if (ch < NCHUNK - 1) STAGE(ch + 1, cur ^ 1);

        const unsigned short* lbuf = &lds[cur][0];
        #pragma unroll 2
        for (int it = 0; it < 8; ++it) {
            const int jw = ch * JC + it * 32;
            const i32x4* ap = (const i32x4*)(aprow + jw);
            i32x4  aj0 = ap[0];
            i32x4  aj1 = ap[1];
            float4 sa  = *(const float4*)(s2b + jw);
            float4 sb  = *(const float4*)(s2b + jw + 4);

            short8v b0 = *(const short8v*)(lbuf + (it * 4 + 0) * 512 + lane * 8);
            short8v b1 = *(const short8v*)(lbuf + (it * 4 + 1) * 512 + lane * 8);
            short8v b2 = *(const short8v*)(lbuf + (it * 4 + 2) * 512 + lane * 8);
            short8v b3 = *(const short8v*)(lbuf + (it * 4 + 3) * 512 + lane * 8);

            float w0, w1, w2, w3, w4, w5, w6, w7;
            #define GAT_EL(wvar, ajv, s2v) do { \
                float e = s1r + (s2v); e = fmaxf(e, 0.2f * e); \
                float ex = __builtin_amdgcn_exp2f(e); \
                wvar = ((ajv) > 0) ? ex : 0.f; dsum += wvar; } while (0);
            GAT_EL(w0, aj0[0], sa.x) GAT_EL(w1, aj0[1], sa.y)
            GAT_EL(w2, aj0[2], sa.z) GAT_EL(w3, aj0[3], sa.w)
            GAT_EL(w4, aj1[0], sb.x) GAT_EL(w5, aj1[1], sb.y)
            GAT_EL(w6, aj1[2], sb.z) GAT_EL(w7, aj1[3], sb.w)
            #undef GAT_EL

            u32x4 au;
            au[0] = cvt_pk_bf16(w0, w1);
            au[1] = cvt_pk_bf16(w2, w3);
            au[2] = cvt_pk_bf16(w4, w5);
            au[3] = cvt_pk_bf16(w6, w7);
            short8v afrag = __builtin_bit_cast(short8v, au);

            acc0 = __builtin_amdgcn_mfma_f32_16x16x32_bf16(afrag, b0, acc0, 0, 0, 0);
            acc1 = __builtin_amdgcn_mfma_f32_16x16x32_bf16(afrag, b1, acc1, 0, 0, 0);
            acc2 = __builtin_amdgcn_mfma_f32_16x16x32_bf16(afrag, b2, acc2, 0, 0, 0);
            acc3 = __builtin_amdgcn_mfma_f32_16x16x32_bf16(afrag, b3, acc3, 0, 0, 0);
        }
        __syncthreads();   // drains the ch+1 stage loads AND fences buffer reuse
    }
    #undef STAGE

    // denominator: combine the 4 k-groups (same l15)
    dsum += __shfl_xor(dsum, 16);
    dsum += __shfl_xor(dsum, 32);
    if (lane < 16) denpart[(size_t)js * N_NODES + rowbase + lane] = dsum;

    // partial numerators: C-frag col = l15 (f = ft*16+l15), local row = g*4+r
    float* np = numpart + ((size_t)js * N_NODES + rowbase) * F_OUT;
    #pragma unroll
    for (int r = 0; r < 4; ++r) {
        const int ro = (g * 4 + r) * F_OUT;
        np[ro +  0 + l15] = acc0[r];
        np[ro + 16 + l15] = acc1[r];
        np[ro + 32 + l15] = acc2[r];
        np[ro + 48 + l15] = acc3[r];
    }
}

// ---------------------------------------------------------------------------
// Kernel 3: combine j-split partials, normalize, ELU.
// ---------------------------------------------------------------------------
__global__ __launch_bounds__(256)
void gat_combine(const float* __restrict__ numpart, const float* __restrict__ denpart,
                 float* __restrict__ out) {
    const int idx = blockIdx.x * 256 + threadIdx.x;   // 0..524287
    const int r = idx >> 6;
    float num = 0.f, den = 0.f;
    #pragma unroll
    for (int c = 0; c < JSPLIT; ++c) {
        num += numpart[(size_t)c * N_NODES * F_OUT + idx];
        den += denpart[(size_t)c * N_NODES + r];
    }
    float h = num / den;
    out[idx] = h > 0.f ? h : __expf(h) - 1.f;
}

extern "C" void kernel_launch(void* const* d_in, const int* in_sizes, int n_in,
                              void* d_out, int out_size, void* d_ws, size_t ws_size,
                              hipStream_t stream) {
    const float* x      = (const float*)d_in[0];
    const int*   adj    = (const int*)d_in[1];
    const float* weight = (const float*)d_in[2];
    const float* a      = (const float*)d_in[3];
    float* out = (float*)d_out;

    // ws: whtf 1MB | s1 32KB | s2 32KB | whf 64KB | wlf 64KB | numpart 8MB | denpart 128KB
    char* ws = (char*)d_ws;
    unsigned short* whtf = (unsigned short*)ws;
    float* s1            = (float*)(ws + 1048576);
    float* s2            = (float*)(ws + 1048576 + 32768);
    unsigned short* whf  = (unsigned short*)(ws + 1048576 + 65536);
    unsigned short* wlf  = (unsigned short*)(ws + 1048576 + 131072);
    float* numpart       = (float*)(ws + 1048576 + 196608);
    float* denpart       = (float*)(ws + 1048576 + 196608 + 8388608);

    gat_wconv<<<16, 256, 0, stream>>>(weight, whf, wlf);
    gat_prep<<<N_NODES / 32, 128, 0, stream>>>(x, whf, wlf, a, whtf, s1, s2);
    gat_main<<<64 * JSPLIT, 512, 0, stream>>>(adj, whtf, s1, s2, numpart, denpart);
    gat_combine<<<N_NODES * F_OUT / 256, 256, 0, stream>>>(numpart, denpart, out);
}

// Round 5
// 85.694 us; speedup vs baseline: 1.4904x; 1.0423x over previous
//
#include <hip/hip_runtime.h>
#include <hip/hip_bf16.h>
#include <cstdint>
#include <cstddef>

#define N_NODES 8192
#define F_IN 512
#define F_OUT 64
#define LOG2E 1.44269504f

#define JSPLIT 8
#define JPB (N_NODES / JSPLIT)   // 1024 j per block
#define JC 256                   // j per staged chunk (32 KB LDS)
#define NCHUNK (JPB / JC)        // 4

typedef __attribute__((ext_vector_type(8))) short short8v;  // 8 bf16 = 4 VGPRs
typedef __attribute__((ext_vector_type(4))) float f32x4;
typedef __attribute__((ext_vector_type(4))) int i32x4;
typedef __attribute__((ext_vector_type(4))) unsigned int u32x4;

static __device__ __forceinline__ unsigned short f2bf(float f) {
    union { float f; unsigned u; } v; v.f = f;
    unsigned u = v.u + 0x7FFFu + ((v.u >> 16) & 1u);   // RNE
    return (unsigned short)(u >> 16);
}
static __device__ __forceinline__ float bf2f(unsigned short b) {
    union { unsigned u; float f; } v; v.u = ((unsigned)b) << 16;
    return v.f;
}
static __device__ __forceinline__ unsigned cvt_pk_bf16(float lo, float hi) {
    unsigned r;
    asm("v_cvt_pk_bf16_f32 %0, %1, %2" : "=v"(r) : "v"(lo), "v"(hi));
    return r;
}

// ---------------------------------------------------------------------------
// Kernel 0: W (512x64 f32) -> fragment-ordered bf16 hi/lo buffers.
// ---------------------------------------------------------------------------
__global__ __launch_bounds__(256)
void gat_wconv(const float* __restrict__ W, unsigned short* __restrict__ whf,
               unsigned short* __restrict__ wlf) {
    const int t = blockIdx.x * 256 + threadIdx.x;   // 0..4095
    const int tile = t >> 6, lane = t & 63;
    const int kt = tile >> 2, ct = tile & 3;
    const int k0 = kt * 32 + ((lane >> 4) << 3);
    const int c  = ct * 16 + (lane & 15);
    short8v h, l;
    #pragma unroll
    for (int i = 0; i < 8; ++i) {
        float v = W[(size_t)(k0 + i) * F_OUT + c];
        unsigned short hb = f2bf(v);
        h[i] = (short)hb;
        l[i] = (short)f2bf(v - bf2f(hb));
    }
    const size_t dst = (size_t)tile * 512 + (size_t)lane * 8;
    *(short8v*)(whf + dst) = h;
    *(short8v*)(wlf + dst) = l;
}

// ---------------------------------------------------------------------------
// Kernel 1: Wh = x@W via bf16 hi/lo split MFMA, K split 2-way across wave
// pairs (256 thr = 4 waves: rt = wv&1 row-tile, kh = wv>>1 K-half).
// All 8 kt x-loads batched (16 dwordx4 in flight). LDS-reduce K-halves.
// ---------------------------------------------------------------------------
__global__ __launch_bounds__(256)
void gat_prep(const float* __restrict__ x, const unsigned short* __restrict__ whf,
              const unsigned short* __restrict__ wlf, const float* __restrict__ a,
              unsigned short* __restrict__ whtf,
              float* __restrict__ s1, float* __restrict__ s2) {
    __shared__ f32x4 red[2][4][64];           // 8 KB K-half partials
    __shared__ unsigned short ldsT[64][40];   // [col][row], 80B rows
    const int tid = threadIdx.x;
    const int lane = tid & 63;
    const int wv = tid >> 6;                  // 0..3
    const int rt = wv & 1;                    // row-tile
    const int kh = wv >> 1;                   // K-half
    const int l15 = lane & 15, g = lane >> 4;
    const int jt = blockIdx.x;                // jtile 0..255
    const int row0 = jt * 32 + rt * 16;

    f32x4 acc[4] = {{0.f,0.f,0.f,0.f},{0.f,0.f,0.f,0.f},{0.f,0.f,0.f,0.f},{0.f,0.f,0.f,0.f}};

    // batch all 8 kt loads for this K-half (16 dwordx4 in flight)
    const float* xp = x + (size_t)(row0 + l15) * F_IN + kh * 256 + g * 8;
    float4 v[16];
    #pragma unroll
    for (int q = 0; q < 8; ++q) {
        v[2 * q]     = *(const float4*)(xp + q * 32);
        v[2 * q + 1] = *(const float4*)(xp + q * 32 + 4);
    }
    #pragma unroll
    for (int q = 0; q < 8; ++q) {
        const int kt = kh * 8 + q;
        float vv[8] = {v[2*q].x, v[2*q].y, v[2*q].z, v[2*q].w,
                       v[2*q+1].x, v[2*q+1].y, v[2*q+1].z, v[2*q+1].w};
        short8v xh, xl;
        #pragma unroll
        for (int i = 0; i < 8; ++i) {
            unsigned short hb = f2bf(vv[i]);
            xh[i] = (short)hb;
            xl[i] = (short)f2bf(vv[i] - bf2f(hb));
        }
        const unsigned short* wp = whf + (size_t)(kt * 4) * 512 + (size_t)lane * 8;
        const unsigned short* lp = wlf + (size_t)(kt * 4) * 512 + (size_t)lane * 8;
        #pragma unroll
        for (int ct = 0; ct < 4; ++ct) {
            short8v wh = *(const short8v*)(wp + ct * 512);
            short8v wl = *(const short8v*)(lp + ct * 512);
            acc[ct] = __builtin_amdgcn_mfma_f32_16x16x32_bf16(xh, wh, acc[ct], 0, 0, 0);
            acc[ct] = __builtin_amdgcn_mfma_f32_16x16x32_bf16(xl, wh, acc[ct], 0, 0, 0);
            acc[ct] = __builtin_amdgcn_mfma_f32_16x16x32_bf16(xh, wl, acc[ct], 0, 0, 0);
        }
    }

    if (kh == 1) {
        #pragma unroll
        for (int ct = 0; ct < 4; ++ct) red[rt][ct][lane] = acc[ct];
    }
    __syncthreads();

    if (kh == 0) {
        #pragma unroll
        for (int ct = 0; ct < 4; ++ct) acc[ct] += red[rt][ct][lane];

        // s1/s2 (scaled by log2e): C-frag col = ct*16+l15, local row = 4g+r
        #pragma unroll
        for (int r = 0; r < 4; ++r) {
            float p1 = 0.f, p2 = 0.f;
            #pragma unroll
            for (int ct = 0; ct < 4; ++ct) {
                p1 = fmaf(acc[ct][r], a[ct * 16 + l15], p1);
                p2 = fmaf(acc[ct][r], a[64 + ct * 16 + l15], p2);
            }
            p1 += __shfl_xor(p1, 1); p2 += __shfl_xor(p2, 1);
            p1 += __shfl_xor(p1, 2); p2 += __shfl_xor(p2, 2);
            p1 += __shfl_xor(p1, 4); p2 += __shfl_xor(p2, 4);
            p1 += __shfl_xor(p1, 8); p2 += __shfl_xor(p2, 8);
            if (l15 == 0) {
                s1[row0 + g * 4 + r] = p1 * LOG2E;
                s2[row0 + g * 4 + r] = p2 * LOG2E;
            }
        }

        // transpose to [col][row] bf16 in LDS
        #pragma unroll
        for (int ct = 0; ct < 4; ++ct) {
            ushort4 pk;
            pk.x = f2bf(acc[ct][0]); pk.y = f2bf(acc[ct][1]);
            pk.z = f2bf(acc[ct][2]); pk.w = f2bf(acc[ct][3]);
            *(ushort4*)&ldsT[ct * 16 + l15][rt * 16 + g * 4] = pk;
        }
    }
    __syncthreads();

    if (kh == 0) {
        #pragma unroll
        for (int fl = 0; fl < 2; ++fl) {
            const int ft = rt * 2 + fl;
            short8v sv = *(const short8v*)&ldsT[ft * 16 + l15][g * 8];
            *(short8v*)(whtf + ((size_t)jt * 4 + ft) * 512 + (size_t)lane * 8) = sv;
        }
    }
}

// ---------------------------------------------------------------------------
// Kernel 2: fused masked-softmax attention + PV via bf16 MFMA.
// Grid 64 rowgroups x 8 jsplits = 512 blocks (2/CU, 4 waves/SIMD).
// 128 rows x 1024 j per block; 32 KB whtf chunks double-buffered in LDS.
// adj loads batched 4 iterations deep (8 dwordx4 in flight per wave).
// ---------------------------------------------------------------------------
__global__ __launch_bounds__(512)
void gat_main(const int* __restrict__ adj, const unsigned short* __restrict__ whtf,
              const float* __restrict__ s1, const float* __restrict__ s2,
              float* __restrict__ numpart, float* __restrict__ denpart) {
    __shared__ unsigned short lds[2][JC * F_OUT];   // 2 x 32 KB
    const int tid  = threadIdx.x;
    const int lane = tid & 63;
    const int wv   = tid >> 6;                // 0..7: row-tile within block
    const int l15  = lane & 15, g = lane >> 4;
    const int rg   = blockIdx.x >> 3;         // 0..63 row-group (128 rows)
    const int js   = blockIdx.x & 7;          // j-split (== XCD id: L2-resident whtf slice)
    const int rowbase = rg * 128 + wv * 16;
    const int row  = rowbase + l15;
    const int j0   = js * JPB;
    const float s1r = s1[row];                // exp2 domain

    const char* gbase = (const char*)whtf + (size_t)j0 * 128;   // 128 B per j column
    const int*   aprow = adj + (size_t)row * N_NODES + j0 + g * 8;
    const float* s2b   = s2 + j0 + g * 8;

    f32x4 acc0 = {0.f, 0.f, 0.f, 0.f};
    f32x4 acc1 = acc0, acc2 = acc0, acc3 = acc0;
    float dsum = 0.f;

    #define STAGE(ch, buf) do { \
        const char* _g = gbase + (size_t)(ch) * 32768 + (size_t)tid * 16; \
        char* _l = (char*)&lds[buf][0] + (size_t)wv * 1024; \
        _Pragma("unroll") \
        for (int _i = 0; _i < 4; ++_i) \
            __builtin_amdgcn_global_load_lds( \
                (const __attribute__((address_space(1))) void*)(_g + _i * 8192), \
                (__attribute__((address_space(3))) void*)(_l + _i * 8192), 16, 0, 0); \
    } while (0)

    STAGE(0, 0);
    __syncthreads();

    for (int ch = 0; ch < NCHUNK; ++ch) {
        const int cur = ch & 1;
        if (ch < NCHUNK - 1) STAGE(ch + 1, cur ^ 1);

        const unsigned short* lbuf = &lds[cur][0];
        #pragma unroll
        for (int itg = 0; itg < 2; ++itg) {
            // batch 4 iterations of adj loads (8 dwordx4 in flight)
            i32x4 aj[8];
            #pragma unroll
            for (int q = 0; q < 4; ++q) {
                const i32x4* ap = (const i32x4*)(aprow + ch * JC + itg * 128 + q * 32);
                aj[2 * q]     = ap[0];
                aj[2 * q + 1] = ap[1];
            }
            #pragma unroll
            for (int q = 0; q < 4; ++q) {
                const int it = itg * 4 + q;
                const int jw = ch * JC + it * 32;
                float4 sa = *(const float4*)(s2b + jw);
                float4 sb = *(const float4*)(s2b + jw + 4);

                short8v b0 = *(const short8v*)(lbuf + (it * 4 + 0) * 512 + lane * 8);
                short8v b1 = *(const short8v*)(lbuf + (it * 4 + 1) * 512 + lane * 8);
                short8v b2 = *(const short8v*)(lbuf + (it * 4 + 2) * 512 + lane * 8);
                short8v b3 = *(const short8v*)(lbuf + (it * 4 + 3) * 512 + lane * 8);

                float w0, w1, w2, w3, w4, w5, w6, w7;
                #define GAT_EL(wvar, ajv, s2v) do { \
                    float e = s1r + (s2v); e = fmaxf(e, 0.2f * e); \
                    float ex = __builtin_amdgcn_exp2f(e); \
                    wvar = ((ajv) > 0) ? ex : 0.f; dsum += wvar; } while (0);
                GAT_EL(w0, aj[2*q][0], sa.x) GAT_EL(w1, aj[2*q][1], sa.y)
                GAT_EL(w2, aj[2*q][2], sa.z) GAT_EL(w3, aj[2*q][3], sa.w)
                GAT_EL(w4, aj[2*q+1][0], sb.x) GAT_EL(w5, aj[2*q+1][1], sb.y)
                GAT_EL(w6, aj[2*q+1][2], sb.z) GAT_EL(w7, aj[2*q+1][3], sb.w)
                #undef GAT_EL

                u32x4 au;
                au[0] = cvt_pk_bf16(w0, w1);
                au[1] = cvt_pk_bf16(w2, w3);
                au[2] = cvt_pk_bf16(w4, w5);
                au[3] = cvt_pk_bf16(w6, w7);
                short8v afrag = __builtin_bit_cast(short8v, au);

                acc0 = __builtin_amdgcn_mfma_f32_16x16x32_bf16(afrag, b0, acc0, 0, 0, 0);
                acc1 = __builtin_amdgcn_mfma_f32_16x16x32_bf16(afrag, b1, acc1, 0, 0, 0);
                acc2 = __builtin_amdgcn_mfma_f32_16x16x32_bf16(afrag, b2, acc2, 0, 0, 0);
                acc3 = __builtin_amdgcn_mfma_f32_16x16x32_bf16(afrag, b3, acc3, 0, 0, 0);
            }
        }
        __syncthreads();   // drains stage loads AND fences buffer reuse
    }
    #undef STAGE

    // denominator: combine the 4 k-groups (same l15)
    dsum += __shfl_xor(dsum, 16);
    dsum += __shfl_xor(dsum, 32);
    if (lane < 16) denpart[(size_t)js * N_NODES + rowbase + lane] = dsum;

    // partial numerators: C-frag col = l15 (f = ft*16+l15), local row = g*4+r
    float* np = numpart + ((size_t)js * N_NODES + rowbase) * F_OUT;
    #pragma unroll
    for (int r = 0; r < 4; ++r) {
        const int ro = (g * 4 + r) * F_OUT;
        np[ro +  0 + l15] = acc0[r];
        np[ro + 16 + l15] = acc1[r];
        np[ro + 32 + l15] = acc2[r];
        np[ro + 48 + l15] = acc3[r];
    }
}

// ---------------------------------------------------------------------------
// Kernel 3: combine j-split partials, normalize, ELU.
// ---------------------------------------------------------------------------
__global__ __launch_bounds__(256)
void gat_combine(const float* __restrict__ numpart, const float* __restrict__ denpart,
                 float* __restrict__ out) {
    const int idx = blockIdx.x * 256 + threadIdx.x;   // 0..524287
    const int r = idx >> 6;
    float num = 0.f, den = 0.f;
    #pragma unroll
    for (int c = 0; c < JSPLIT; ++c) {
        num += numpart[(size_t)c * N_NODES * F_OUT + idx];
        den += denpart[(size_t)c * N_NODES + r];
    }
    float h = num / den;
    out[idx] = h > 0.f ? h : __expf(h) - 1.f;
}

extern "C" void kernel_launch(void* const* d_in, const int* in_sizes, int n_in,
                              void* d_out, int out_size, void* d_ws, size_t ws_size,
                              hipStream_t stream) {
    const float* x      = (const float*)d_in[0];
    const int*   adj    = (const int*)d_in[1];
    const float* weight = (const float*)d_in[2];
    const float* a      = (const float*)d_in[3];
    float* out = (float*)d_out;

    // ws: whtf 1MB | s1 32KB | s2 32KB | whf 64KB | wlf 64KB | numpart 16MB | denpart 256KB
    char* ws = (char*)d_ws;
    unsigned short* whtf = (unsigned short*)ws;
    float* s1            = (float*)(ws + 1048576);
    float* s2            = (float*)(ws + 1048576 + 32768);
    unsigned short* whf  = (unsigned short*)(ws + 1048576 + 65536);
    unsigned short* wlf  = (unsigned short*)(ws + 1048576 + 131072);
    float* numpart       = (float*)(ws + 1048576 + 196608);
    float* denpart       = (float*)(ws + 1048576 + 196608 + (size_t)JSPLIT * N_NODES * F_OUT * 4);

    gat_wconv<<<16, 256, 0, stream>>>(weight, whf, wlf);
    gat_prep<<<N_NODES / 32, 256, 0, stream>>>(x, whf, wlf, a, whtf, s1, s2);
    gat_main<<<64 * JSPLIT, 512, 0, stream>>>(adj, whtf, s1, s2, numpart, denpart);
    gat_combine<<<N_NODES * F_OUT / 256, 256, 0, stream>>>(numpart, denpart, out);
}